// Round 1
// baseline (73.768 us; speedup 1.0000x reference)
//
#include <hip/hip_runtime.h>

// LTPE: y(p) = x(p) - sum_j w_j * x(p + off_j), zero-padded borders,
// then instance-norm over HxW per image: (y - mean) * rsqrt(var + 4e-5).
// (The reference's out = 0.5*y + 0.5; instance norm is affine-invariant,
//  with eps folding 1e-5 -> 4e-5.)

#define HH 1024
#define WW 1024
#define NIMG 32
#define NBLK 64                 // blocks per image (stats/norm)
#define ROWS_PER_BLK (HH / NBLK) // 16
#define TPB 256                 // = WW/4 float4 columns per row

// weights: j=0..7 -> 2^j/255, offsets (dy,dx):
// j0 (0,-1), j1 (1,-1), j2 (1,0), j3 (1,1), j4 (0,1), j5 (-1,1), j6 (-1,0), j7 (-1,-1)
__device__ __forceinline__ void compute_y(const float* up, const float* mid,
                                          const float* dn, float* y) {
    const float w0 = 1.f / 255.f,  w1 = 2.f / 255.f,  w2 = 4.f / 255.f,
                w3 = 8.f / 255.f,  w4 = 16.f / 255.f, w5 = 32.f / 255.f,
                w6 = 64.f / 255.f, w7 = 128.f / 255.f;
#pragma unroll
    for (int k = 0; k < 4; ++k) {
        float s = w0 * mid[k] + w4 * mid[k + 2]
                + w1 * dn[k]  + w2 * dn[k + 1] + w3 * dn[k + 2]
                + w7 * up[k]  + w6 * up[k + 1] + w5 * up[k + 2];
        y[k] = mid[k + 1] - s;
    }
}

// buf[0]=left halo, buf[1..4]=float4, buf[5]=right halo
__device__ __forceinline__ void load_row(const float* __restrict__ row, int c,
                                         float* buf) {
    const float4 v = reinterpret_cast<const float4*>(row)[c];
    buf[0] = (c > 0) ? row[4 * c - 1] : 0.f;
    buf[1] = v.x; buf[2] = v.y; buf[3] = v.z; buf[4] = v.w;
    buf[5] = (c < TPB - 1) ? row[4 * c + 4] : 0.f;
}

__device__ __forceinline__ void zero_row(float* buf) {
#pragma unroll
    for (int k = 0; k < 6; ++k) buf[k] = 0.f;
}

__global__ __launch_bounds__(TPB) void ltpe_stats(const float* __restrict__ x,
                                                  float* __restrict__ partials) {
    const int img = blockIdx.x / NBLK;
    const int blk = blockIdx.x % NBLK;
    const int c = threadIdx.x;
    const float* base = x + (size_t)img * HH * WW;
    const int r0 = blk * ROWS_PER_BLK;

    float up[6], mid[6], dn[6];
    if (r0 > 0) load_row(base + (size_t)(r0 - 1) * WW, c, up); else zero_row(up);
    load_row(base + (size_t)r0 * WW, c, mid);

    float s = 0.f, ss = 0.f;
    for (int i = 0; i < ROWS_PER_BLK; ++i) {
        const int r = r0 + i;
        if (r + 1 < HH) load_row(base + (size_t)(r + 1) * WW, c, dn);
        else zero_row(dn);
        float y[4];
        compute_y(up, mid, dn, y);
#pragma unroll
        for (int k = 0; k < 4; ++k) { s += y[k]; ss = fmaf(y[k], y[k], ss); }
#pragma unroll
        for (int k = 0; k < 6; ++k) { up[k] = mid[k]; mid[k] = dn[k]; }
    }

    // block reduction: wave64 shuffle, then LDS across 4 waves
#pragma unroll
    for (int off = 32; off > 0; off >>= 1) {
        s += __shfl_down(s, off);
        ss += __shfl_down(ss, off);
    }
    __shared__ float sh[8];
    const int wave = threadIdx.x >> 6;
    const int lane = threadIdx.x & 63;
    if (lane == 0) { sh[wave] = s; sh[4 + wave] = ss; }
    __syncthreads();
    if (threadIdx.x == 0) {
        float S = sh[0] + sh[1] + sh[2] + sh[3];
        float SS = sh[4] + sh[5] + sh[6] + sh[7];
        partials[img * NBLK + blk] = S;
        partials[NIMG * NBLK + img * NBLK + blk] = SS;
    }
}

__global__ __launch_bounds__(64) void ltpe_reduce(const float* __restrict__ partials,
                                                  float* __restrict__ stats) {
    const int img = blockIdx.x;
    const int t = threadIdx.x;
    double S = (double)partials[img * NBLK + t];
    double SS = (double)partials[NIMG * NBLK + img * NBLK + t];
#pragma unroll
    for (int off = 32; off > 0; off >>= 1) {
        S += __shfl_down(S, off);
        SS += __shfl_down(SS, off);
    }
    if (t == 0) {
        const double N = (double)HH * (double)WW;
        const double mean = S / N;
        const double var = SS / N - mean * mean;
        const double scale = 1.0 / sqrt(var + 4e-5); // 4*eps folds the 0.5 factor
        stats[img * 2 + 0] = (float)mean;
        stats[img * 2 + 1] = (float)scale;
    }
}

__global__ __launch_bounds__(TPB) void ltpe_norm(const float* __restrict__ x,
                                                 const float* __restrict__ stats,
                                                 float* __restrict__ out) {
    const int img = blockIdx.x / NBLK;
    const int blk = blockIdx.x % NBLK;
    const int c = threadIdx.x;
    const float* base = x + (size_t)img * HH * WW;
    float* obase = out + (size_t)img * HH * WW;
    const int r0 = blk * ROWS_PER_BLK;

    const float mean = stats[img * 2 + 0];
    const float scale = stats[img * 2 + 1];

    float up[6], mid[6], dn[6];
    if (r0 > 0) load_row(base + (size_t)(r0 - 1) * WW, c, up); else zero_row(up);
    load_row(base + (size_t)r0 * WW, c, mid);

    for (int i = 0; i < ROWS_PER_BLK; ++i) {
        const int r = r0 + i;
        if (r + 1 < HH) load_row(base + (size_t)(r + 1) * WW, c, dn);
        else zero_row(dn);
        float y[4];
        compute_y(up, mid, dn, y);
        float4 o;
        o.x = (y[0] - mean) * scale;
        o.y = (y[1] - mean) * scale;
        o.z = (y[2] - mean) * scale;
        o.w = (y[3] - mean) * scale;
        reinterpret_cast<float4*>(obase + (size_t)r * WW)[c] = o;
#pragma unroll
        for (int k = 0; k < 6; ++k) { up[k] = mid[k]; mid[k] = dn[k]; }
    }
}

extern "C" void kernel_launch(void* const* d_in, const int* in_sizes, int n_in,
                              void* d_out, int out_size, void* d_ws, size_t ws_size,
                              hipStream_t stream) {
    const float* x = (const float*)d_in[0];
    float* out = (float*)d_out;
    // ws layout: [NIMG*NBLK sums][NIMG*NBLK sumsqs][NIMG*2 stats]
    float* partials = (float*)d_ws;
    float* stats = partials + 2 * NIMG * NBLK;

    ltpe_stats<<<NIMG * NBLK, TPB, 0, stream>>>(x, partials);
    ltpe_reduce<<<NIMG, 64, 0, stream>>>(partials, stats);
    ltpe_norm<<<NIMG * NBLK, TPB, 0, stream>>>(x, stats, out);
}

// Round 2
// 72.210 us; speedup vs baseline: 1.0216x; 1.0216x over previous
//
#include <hip/hip_runtime.h>

// LTPE: y(p) = x(p) - sum_j w_j * x(p + off_j), zero-padded borders,
// then instance-norm over HxW per image: (y - mean) * rsqrt(var + 4e-5).
// (The reference's out = 0.5*y + 0.5; instance norm is affine-invariant,
//  with eps folding 1e-5 -> 4e-5.)

#define HH 1024
#define WW 1024
#define NIMG 32
#define NBLK 64                  // blocks per image (stats/norm)
#define ROWS_PER_BLK (HH / NBLK) // 16
#define TPB 256                  // = WW/4 float4 columns per row

typedef float vfloat4 __attribute__((ext_vector_type(4)));

// weights: j=0..7 -> 2^j/255, offsets (dy,dx):
// j0 (0,-1), j1 (1,-1), j2 (1,0), j3 (1,1), j4 (0,1), j5 (-1,1), j6 (-1,0), j7 (-1,-1)
__device__ __forceinline__ void compute_y(const float* up, const float* mid,
                                          const float* dn, float* y) {
    const float w0 = 1.f / 255.f,  w1 = 2.f / 255.f,  w2 = 4.f / 255.f,
                w3 = 8.f / 255.f,  w4 = 16.f / 255.f, w5 = 32.f / 255.f,
                w6 = 64.f / 255.f, w7 = 128.f / 255.f;
#pragma unroll
    for (int k = 0; k < 4; ++k) {
        float s = w0 * mid[k] + w4 * mid[k + 2]
                + w1 * dn[k]  + w2 * dn[k + 1] + w3 * dn[k + 2]
                + w7 * up[k]  + w6 * up[k + 1] + w5 * up[k + 2];
        y[k] = mid[k + 1] - s;
    }
}

// buf[0]=left halo, buf[1..4]=vfloat4, buf[5]=right halo
__device__ __forceinline__ void load_row(const float* __restrict__ row, int c,
                                         float* buf) {
    const vfloat4 v = reinterpret_cast<const vfloat4*>(row)[c];
    buf[0] = (c > 0) ? row[4 * c - 1] : 0.f;
    buf[1] = v.x; buf[2] = v.y; buf[3] = v.z; buf[4] = v.w;
    buf[5] = (c < TPB - 1) ? row[4 * c + 4] : 0.f;
}

__device__ __forceinline__ void zero_row(float* buf) {
#pragma unroll
    for (int k = 0; k < 6; ++k) buf[k] = 0.f;
}

__global__ __launch_bounds__(TPB) void ltpe_stats(const float* __restrict__ x,
                                                  float* __restrict__ partials) {
    const int img = blockIdx.x / NBLK;
    const int blk = blockIdx.x % NBLK;
    const int c = threadIdx.x;
    const float* base = x + (size_t)img * HH * WW;
    const int r0 = blk * ROWS_PER_BLK;

    float up[6], mid[6], dn[6];
    if (r0 > 0) load_row(base + (size_t)(r0 - 1) * WW, c, up); else zero_row(up);
    load_row(base + (size_t)r0 * WW, c, mid);

    float s = 0.f, ss = 0.f;
    for (int i = 0; i < ROWS_PER_BLK; ++i) {
        const int r = r0 + i;
        if (r + 1 < HH) load_row(base + (size_t)(r + 1) * WW, c, dn);
        else zero_row(dn);
        float y[4];
        compute_y(up, mid, dn, y);
#pragma unroll
        for (int k = 0; k < 4; ++k) { s += y[k]; ss = fmaf(y[k], y[k], ss); }
#pragma unroll
        for (int k = 0; k < 6; ++k) { up[k] = mid[k]; mid[k] = dn[k]; }
    }

    // block reduction: wave64 shuffle, then LDS across 4 waves
#pragma unroll
    for (int off = 32; off > 0; off >>= 1) {
        s += __shfl_down(s, off);
        ss += __shfl_down(ss, off);
    }
    __shared__ float sh[8];
    const int wave = threadIdx.x >> 6;
    const int lane = threadIdx.x & 63;
    if (lane == 0) { sh[wave] = s; sh[4 + wave] = ss; }
    __syncthreads();
    if (threadIdx.x == 0) {
        float S = sh[0] + sh[1] + sh[2] + sh[3];
        float SS = sh[4] + sh[5] + sh[6] + sh[7];
        partials[img * NBLK + blk] = S;
        partials[NIMG * NBLK + img * NBLK + blk] = SS;
    }
}

__global__ __launch_bounds__(TPB) void ltpe_norm(const float* __restrict__ x,
                                                 const float* __restrict__ partials,
                                                 float* __restrict__ out) {
    const int img = blockIdx.x / NBLK;
    const int blk = blockIdx.x % NBLK;
    const int c = threadIdx.x;

    // Per-block redundant final reduction of this image's 64 partial sums
    // (double precision, one wave). Removes the separate reduce kernel.
    __shared__ float sh_stats[2];
    if (threadIdx.x < 64) {
        const int lane = threadIdx.x;
        double S = (double)partials[img * NBLK + lane];
        double SS = (double)partials[NIMG * NBLK + img * NBLK + lane];
#pragma unroll
        for (int off = 32; off > 0; off >>= 1) {
            S += __shfl_down(S, off);
            SS += __shfl_down(SS, off);
        }
        if (lane == 0) {
            const double N = (double)HH * (double)WW;
            const double mean = S / N;
            const double var = SS / N - mean * mean;
            sh_stats[0] = (float)mean;
            sh_stats[1] = (float)(1.0 / sqrt(var + 4e-5)); // 4*eps folds the 0.5
        }
    }
    __syncthreads();
    const float mean = sh_stats[0];
    const float scale = sh_stats[1];

    const float* base = x + (size_t)img * HH * WW;
    float* obase = out + (size_t)img * HH * WW;
    const int r0 = blk * ROWS_PER_BLK;

    float up[6], mid[6], dn[6];
    if (r0 > 0) load_row(base + (size_t)(r0 - 1) * WW, c, up); else zero_row(up);
    load_row(base + (size_t)r0 * WW, c, mid);

    for (int i = 0; i < ROWS_PER_BLK; ++i) {
        const int r = r0 + i;
        if (r + 1 < HH) load_row(base + (size_t)(r + 1) * WW, c, dn);
        else zero_row(dn);
        float y[4];
        compute_y(up, mid, dn, y);
        vfloat4 o;
        o.x = (y[0] - mean) * scale;
        o.y = (y[1] - mean) * scale;
        o.z = (y[2] - mean) * scale;
        o.w = (y[3] - mean) * scale;
        // Non-temporal: don't let the 128 MB output stream evict x from L3 —
        // the norm pass's x reads should stay L3 hits.
        vfloat4* op = reinterpret_cast<vfloat4*>(obase + (size_t)r * WW) + c;
        __builtin_nontemporal_store(o, op);
#pragma unroll
        for (int k = 0; k < 6; ++k) { up[k] = mid[k]; mid[k] = dn[k]; }
    }
}

extern "C" void kernel_launch(void* const* d_in, const int* in_sizes, int n_in,
                              void* d_out, int out_size, void* d_ws, size_t ws_size,
                              hipStream_t stream) {
    const float* x = (const float*)d_in[0];
    float* out = (float*)d_out;
    // ws layout: [NIMG*NBLK sums][NIMG*NBLK sumsqs]
    float* partials = (float*)d_ws;

    ltpe_stats<<<NIMG * NBLK, TPB, 0, stream>>>(x, partials);
    ltpe_norm<<<NIMG * NBLK, TPB, 0, stream>>>(x, partials, out);
}